// Round 10
// baseline (341.618 us; speedup 1.0000x reference)
//
#include <hip/hip_runtime.h>
#include <math.h>

#define NVEC 32768   // 32*32*32 vectors
#define NE   1024    // codebook entries
#define ED   64      // embedding dim
#define TOT  2097152 // NVEC*ED total z elements
#define NCHUNK 8     // code chunks in k_dist
#define CHUNK  128   // codes per chunk

// d_out offsets (in floats): loss | z_q_st | perplexity | min_encodings | idx
#define O_LOSS   0
#define O_ZQ     1
#define O_PERP   2097153
#define O_MINENC 2097154
#define O_IDX    35651586

// d_ws offsets (in floats). No ws memset: every cell read has a producer.
#define W_PDIST  0        // [8][32768] chunk best d
#define W_PIDX   262144   // [8][32768] chunk best idx (int); chunk-0 slot -> final idx
#define W_CS     524288   // [1024]
#define W_SUMENC 525312   // [1024*64]
#define W_NEWEMB 590848   // [1024*64]
#define W_LOSSP  656384   // [2048]

// R9 post-mortem: the register allocator will NOT keep a 64-float z vector
// live (VGPR stayed 40-52 across launch_bounds/waves_per_eu/asm-pin attempts);
// it re-reads z from L2 every iteration (~4.3 GB L2 traffic ~= the whole
// 97 µs). Fix: stage 2*z in LDS ([quad][tid][4] layout -> conflict-free
// 16B/lane ds_read_b128), dims 56..63 in 8 registers to fit 57.8 KB LDS.
// zsq accumulated np-pairwise-order during staging (no 64-array in source).
// Numerics bit-identical to R9 (passed): same FMA chain order, same pairwise
// zsq/esq, same d formula, same ascending-k strict-< tie-break.
__global__ void __launch_bounds__(256) k_dist(const float* __restrict__ z,
                                              const float* __restrict__ emb,
                                              float* __restrict__ pdist,
                                              int* __restrict__ pidx) {
    __shared__ __align__(16) float s_z2[14336];  // 2*z dims 0..55: [cq][tid][4]
    __shared__ float s_esq[CHUNK];
    int tid = threadIdx.x;
    int k0 = blockIdx.y * CHUNK;

    if (tid < CHUNK) {  // streamed np-pairwise ||e||^2 (no e[64] array)
        const float* ep = emb + (size_t)(k0 + tid) * ED;
        float r[8];
#pragma unroll
        for (int j = 0; j < 8; ++j) r[j] = __fmul_rn(ep[j], ep[j]);
#pragma unroll
        for (int i = 8; i < 64; i += 8)
#pragma unroll
            for (int j = 0; j < 8; ++j)
                r[j] = __fadd_rn(r[j], __fmul_rn(ep[i + j], ep[i + j]));
        s_esq[tid] = __fadd_rn(
            __fadd_rn(__fadd_rn(r[0], r[1]), __fadd_rn(r[2], r[3])),
            __fadd_rn(__fadd_rn(r[4], r[5]), __fadd_rn(r[6], r[7])));
    }

    int n = blockIdx.x * 256 + tid;
    int b = n >> 10, hw = n & 1023;
    const float* zp = z + b * 65536 + hw;  // element c at zp[c*1024]
    float r[8];
    float zr[8];  // 2*z dims 56..63 stay in registers
#pragma unroll
    for (int cq = 0; cq < 16; ++cq) {
        float4 v4;
#pragma unroll
        for (int u = 0; u < 4; ++u) {
            int c = cq * 4 + u;
            float v = zp[c << 10];
            float sq = __fmul_rn(v, v);
            if (c < 8) r[c] = sq;                          // np pairwise: r[c&7]
            else       r[c & 7] = __fadd_rn(r[c & 7], sq); // ascending-i order
            (&v4.x)[u] = __fmul_rn(2.0f, v);               // (2.0*zf), exact
        }
        if (cq < 14) {
            *(float4*)(s_z2 + cq * 1024 + tid * 4) = v4;   // 16B/lane, conflict-free
        } else {
            zr[(cq - 14) * 4 + 0] = v4.x;
            zr[(cq - 14) * 4 + 1] = v4.y;
            zr[(cq - 14) * 4 + 2] = v4.z;
            zr[(cq - 14) * 4 + 3] = v4.w;
        }
    }
    float zsq = __fadd_rn(
        __fadd_rn(__fadd_rn(r[0], r[1]), __fadd_rn(r[2], r[3])),
        __fadd_rn(__fadd_rn(r[4], r[5]), __fadd_rn(r[6], r[7])));
    __syncthreads();

    float best = 3.4e38f;
    int bi = k0;
#pragma unroll 2
    for (int kk = 0; kk < CHUNK; kk += 2) {
        const float4* ep0 = (const float4*)(emb + (size_t)(k0 + kk) * ED);
        const float4* ep1 = ep0 + 16;
        float a0 = 0.f, a1 = 0.f;  // two sequential chains (2-way ILP)
#pragma unroll
        for (int j = 0; j < 14; ++j) {
            float4 zq = *(const float4*)(s_z2 + j * 1024 + tid * 4);
            float4 e0 = ep0[j];
            float4 e1 = ep1[j];
            a0 = __fmaf_rn(zq.x, e0.x, a0); a1 = __fmaf_rn(zq.x, e1.x, a1);
            a0 = __fmaf_rn(zq.y, e0.y, a0); a1 = __fmaf_rn(zq.y, e1.y, a1);
            a0 = __fmaf_rn(zq.z, e0.z, a0); a1 = __fmaf_rn(zq.z, e1.z, a1);
            a0 = __fmaf_rn(zq.w, e0.w, a0); a1 = __fmaf_rn(zq.w, e1.w, a1);
        }
#pragma unroll
        for (int j = 14; j < 16; ++j) {
            float4 e0 = ep0[j];
            float4 e1 = ep1[j];
            int o = (j - 14) * 4;
            a0 = __fmaf_rn(zr[o + 0], e0.x, a0); a1 = __fmaf_rn(zr[o + 0], e1.x, a1);
            a0 = __fmaf_rn(zr[o + 1], e0.y, a0); a1 = __fmaf_rn(zr[o + 1], e1.y, a1);
            a0 = __fmaf_rn(zr[o + 2], e0.z, a0); a1 = __fmaf_rn(zr[o + 2], e1.z, a1);
            a0 = __fmaf_rn(zr[o + 3], e0.w, a0); a1 = __fmaf_rn(zr[o + 3], e1.w, a1);
        }
        float d0 = __fsub_rn(__fadd_rn(zsq, s_esq[kk]), a0);
        float d1 = __fsub_rn(__fadd_rn(zsq, s_esq[kk + 1]), a1);
        if (d0 < best) { best = d0; bi = k0 + kk; }      // ascending k, strict <
        if (d1 < best) { best = d1; bi = k0 + kk + 1; }  // -> np first-index ties
    }
    pdist[blockIdx.y * NVEC + n] = best;
    pidx[blockIdx.y * NVEC + n] = bi;
}

// Merge 8 chunks (ascending -> first-index ties); write idx; write FULL one-hot
// rows (replaces memset). R9 ran this at 128 blocks = 0.5 block/CU — half the
// chip idle on a 134 MB write. Now 512 blocks x 64 rows (2 blocks/CU).
__global__ void __launch_bounds__(256) k_combine(const float* __restrict__ pdist,
                                                 int* __restrict__ pidx,
                                                 float* __restrict__ out) {
    __shared__ int sbi[64];
    int n0 = blockIdx.x * 64;
    if (threadIdx.x < 64) {
        int n = n0 + threadIdx.x;
        float best = pdist[n];
        int bi = pidx[n];
#pragma unroll
        for (int q = 1; q < NCHUNK; ++q) {
            float d = pdist[q * NVEC + n];
            int i = pidx[q * NVEC + n];
            if (d < best) { best = d; bi = i; }
        }
        pidx[n] = bi;  // final idx (own slot only)
        out[O_IDX + n] = (float)bi;
        sbi[threadIdx.x] = bi;
    }
    __syncthreads();
    int wave = threadIdx.x >> 6, lane = threadIdx.x & 63;
    size_t base = (size_t)O_MINENC + (size_t)n0 * NE;
    for (int r = wave; r < 64; r += 4) {
        int rbi = sbi[r];
        float* rp = out + base + (size_t)r * NE;
#pragma unroll
        for (int s = 0; s < 8; ++s) {
            int col = s * 128 + lane * 2;
            float2 v;
            v.x = (col == rbi) ? 1.0f : 0.0f;
            v.y = (col + 1 == rbi) ? 1.0f : 0.0f;
            *(float2*)(rp + col) = v;
        }
    }
}

// Gather-based segment sum: one block per code k, 4 waves. Ballot-scan idx;
// members accumulated lane=element; popcount -> cs. Deterministic. No atomics.
__global__ void __launch_bounds__(256) k_sumenc(const int* __restrict__ idx,
                                                const float* __restrict__ z,
                                                float* __restrict__ cs,
                                                float* __restrict__ sumenc) {
    int k = blockIdx.x;
    int wave = threadIdx.x >> 6, lane = threadIdx.x & 63;
    float acc = 0.f;
    int cnt = 0;
    int base = wave * 8192;
    for (int it = 0; it < 128; ++it) {
        int n0 = base + it * 64;
        int idv = idx[n0 + lane];
        unsigned long long m = __ballot(idv == k);
        cnt += __popcll(m);
        while (m) {
            int bit = __ffsll((unsigned long long)m) - 1;  // ascending n
            m &= m - 1;
            int n = n0 + bit;
            int b = n >> 10, hw = n & 1023;
            acc = __fadd_rn(acc, z[b * 65536 + lane * 1024 + hw]);  // element c = lane
        }
    }
    __shared__ float sacc[4][64];
    __shared__ int scnt[4];
    sacc[wave][lane] = acc;
    if (lane == 0) scnt[wave] = cnt;
    __syncthreads();
    if (wave == 0) {
        float t = __fadd_rn(__fadd_rn(sacc[0][lane], sacc[1][lane]),
                            __fadd_rn(sacc[2][lane], sacc[3][lane]));
        sumenc[k * ED + lane] = t;
        if (lane == 0) cs[k] = (float)(scnt[0] + scnt[1] + scnt[2] + scnt[3]);
    }
}

// Single block, 1024 threads: EMA cluster-size + ntot/entropy reductions +
// perplexity + codebook update. Fused.
__global__ void __launch_bounds__(1024) k_ema(const float* __restrict__ ema_cs,
                                              const float* __restrict__ ema_w,
                                              const float* __restrict__ cs,
                                              const float* __restrict__ sumenc,
                                              float* __restrict__ newemb,
                                              float* __restrict__ out) {
    int k = threadIdx.x;  // 0..1023 == NE
    float c = cs[k];
    float ncs = 0.99f * ema_cs[k] + (1.0f - 0.99f) * c;
    float p = c * (1.0f / (float)NVEC);
    float e = p * logf(p + 1e-10f);
    float rn_ = ncs, re_ = e;
#pragma unroll
    for (int o = 32; o > 0; o >>= 1) {
        rn_ += __shfl_down(rn_, o, 64);
        re_ += __shfl_down(re_, o, 64);
    }
    __shared__ float sn[16], se_[16];
    __shared__ float s_n;
    int wave = k >> 6, lane = k & 63;
    if (lane == 0) { sn[wave] = rn_; se_[wave] = re_; }
    __syncthreads();
    if (k == 0) {
        float tn = 0.f, te = 0.f;
#pragma unroll
        for (int w = 0; w < 16; ++w) { tn += sn[w]; te += se_[w]; }
        s_n = tn;
        out[O_PERP] = expf(-te);
    }
    __syncthreads();
    float nt = s_n;
    float csn = (ncs + 1e-5f) / (nt + 1024.0f * 1e-5f) * nt;
    __shared__ float s_csn[NE];
    s_csn[k] = csn;
    __syncthreads();
    for (int t = k; t < NE * ED; t += 1024) {  // coalesced
        float nw = 0.99f * ema_w[t] + (1.0f - 0.99f) * sumenc[t];
        newemb[t] = nw / s_csn[t >> 6];
    }
}

// 2048 blocks x 256 threads x 4 elems. Per-block partial loss, one plain store.
__global__ void __launch_bounds__(256) k_zq(const float* __restrict__ z,
                                            const int* __restrict__ idx,
                                            const float* __restrict__ newemb,
                                            float* __restrict__ out,
                                            float* __restrict__ lossp) {
    float local = 0.f;
#pragma unroll
    for (int i = 0; i < 4; ++i) {
        int t = blockIdx.x * 256 + threadIdx.x + i * 524288;
        int b = t >> 16, c = (t >> 10) & 63, hw = t & 1023;
        int n = (b << 10) | hw;
        float e = newemb[idx[n] * ED + c];
        float zv = z[t];
        float diff = e - zv;             // z_q - z
        out[O_ZQ + t] = zv + diff;       // straight-through: z + (z_q - z)
        local = fmaf(diff, diff, local);
    }
#pragma unroll
    for (int o = 32; o > 0; o >>= 1) local += __shfl_down(local, o, 64);
    __shared__ float sp[4];
    int wave = threadIdx.x >> 6;
    if ((threadIdx.x & 63) == 0) sp[wave] = local;
    __syncthreads();
    if (threadIdx.x == 0)
        lossp[blockIdx.x] = (sp[0] + sp[1]) + (sp[2] + sp[3]);
}

// One block, 256 threads: reduce 2048 partials -> loss.
__global__ void __launch_bounds__(256) k_fin(const float* __restrict__ lossp,
                                             float* __restrict__ out) {
    float v = 0.f;
#pragma unroll
    for (int i = 0; i < 8; ++i) v += lossp[i * 256 + threadIdx.x];
#pragma unroll
    for (int o = 32; o > 0; o >>= 1) v += __shfl_down(v, o, 64);
    __shared__ float sp[4];
    int wave = threadIdx.x >> 6;
    if ((threadIdx.x & 63) == 0) sp[wave] = v;
    __syncthreads();
    if (threadIdx.x == 0)
        out[O_LOSS] = 0.25f * (((sp[0] + sp[1]) + (sp[2] + sp[3])) * (1.0f / (float)TOT));
}

extern "C" void kernel_launch(void* const* d_in, const int* in_sizes, int n_in,
                              void* d_out, int out_size, void* d_ws, size_t ws_size,
                              hipStream_t stream) {
    const float* z      = (const float*)d_in[0];
    const float* emb    = (const float*)d_in[1];
    const float* ema_cs = (const float*)d_in[2];
    const float* ema_w  = (const float*)d_in[3];
    float* out = (float*)d_out;
    float* ws  = (float*)d_ws;

    k_dist<<<dim3(128, NCHUNK), 256, 0, stream>>>(z, emb, ws + W_PDIST,
                                                  (int*)(ws + W_PIDX));
    k_combine<<<512, 256, 0, stream>>>(ws + W_PDIST, (int*)(ws + W_PIDX), out);
    k_sumenc<<<NE, 256, 0, stream>>>((const int*)(ws + W_PIDX), z, ws + W_CS,
                                     ws + W_SUMENC);
    k_ema<<<1, 1024, 0, stream>>>(ema_cs, ema_w, ws + W_CS, ws + W_SUMENC,
                                  ws + W_NEWEMB, out);
    k_zq<<<2048, 256, 0, stream>>>(z, (const int*)(ws + W_PIDX), ws + W_NEWEMB, out,
                                   ws + W_LOSSP);
    k_fin<<<1, 256, 0, stream>>>(ws + W_LOSSP, out);
}

// Round 11
// 287.244 us; speedup vs baseline: 1.1893x; 1.1893x over previous
//
#include <hip/hip_runtime.h>
#include <math.h>

#define NVEC 32768   // 32*32*32 vectors
#define NE   1024    // codebook entries
#define ED   64      // embedding dim
#define TOT  2097152 // NVEC*ED total z elements
#define NCHUNK 8     // code chunks in k_dist
#define CHUNK  128   // codes per chunk
#define MT     64    // vectors per k_dist block

// d_out offsets (in floats): loss | z_q_st | perplexity | min_encodings | idx
#define O_LOSS   0
#define O_ZQ     1
#define O_PERP   2097153
#define O_MINENC 2097154
#define O_IDX    35651586

// d_ws offsets (in floats). No ws memset: every cell read has a producer.
#define W_PDIST  0        // [8][32768] chunk best d
#define W_PIDX   262144   // [8][32768] chunk best idx (int); chunk-0 slot -> final idx
#define W_CS     524288   // [1024]
#define W_SUMENC 525312   // [1024*64]
#define W_NEWEMB 590848   // [1024*64]
#define W_LOSSP  656384   // [2048]

// R10 post-mortem: both "zv in registers" (allocator refuses, re-reads L2,
// 97 µs) and "zv fully in LDS" (57.8 KB -> 2 waves/SIMD, LDS-pipe exposed,
// 126 µs) fail because one-thread-per-vector needs 64 live z floats.
// Restructure as register-blocked SGEMM: 64x128 output tile per block,
// 4(m)x8(k) accumulators per thread (32 VGPRs, non-rematerializable -> the
// allocator MUST keep them). A=[c][m] 2z (16 KB), B=[c][k] e (stride 132,
// 33 KB). 3 ds_read_b128 + 32 FMAs per c-step -> FMA-bound. 49.8 KB LDS ->
// 3 blocks/CU. Numerics bit-identical to R9/R10 (passed): same ascending-c
// FMA chain per (n,k), zsq = 0.25*pairwise((2z)^2) (exact pow2 scaling),
// same esq, same ascending-k strict-< ties at all 3 merge levels.
__global__ void __launch_bounds__(256, 3) k_dist(const float* __restrict__ z,
                                                 const float* __restrict__ emb,
                                                 float* __restrict__ pdist,
                                                 int* __restrict__ pidx) {
    __shared__ __align__(16) float s_a[64 * 64];    // [c][m] : 2*z
    __shared__ __align__(16) float s_b[64 * 132];   // [c][k] : e, padded stride
    __shared__ float s_esq[CHUNK];
    __shared__ float s_zsq[MT];

    int tid = threadIdx.x;
    int k0 = blockIdx.y * CHUNK;
    int n0 = blockIdx.x * MT;
    int b = n0 >> 10, hw0 = n0 & 1023;  // MT=64 tile never crosses a b boundary
    const float* zb = z + b * 65536 + hw0;

    // Stage A: 64c x 64m = 1024 float4, coalesced; store 2*z (exact x2)
#pragma unroll
    for (int j = 0; j < 4; ++j) {
        int f4i = j * 256 + tid;
        int c = f4i >> 4, pos = (f4i & 15) * 4;
        float4 v = *(const float4*)(zb + (c << 10) + pos);
        v.x = __fmul_rn(2.0f, v.x);
        v.y = __fmul_rn(2.0f, v.y);
        v.z = __fmul_rn(2.0f, v.z);
        v.w = __fmul_rn(2.0f, v.w);
        *(float4*)(s_a + c * 64 + pos) = v;
    }
    // Stage B transposed: 128k x 64c, coalesced global f4 reads, scalar LDS
    // stores at stride 132 (2-way bank aliasing only -> free)
#pragma unroll
    for (int j = 0; j < 8; ++j) {
        int f4i = j * 256 + tid;
        int kl = f4i >> 4, c0 = (f4i & 15) * 4;
        float4 v = *(const float4*)(emb + (size_t)(k0 + kl) * ED + c0);
        s_b[(c0 + 0) * 132 + kl] = v.x;
        s_b[(c0 + 1) * 132 + kl] = v.y;
        s_b[(c0 + 2) * 132 + kl] = v.z;
        s_b[(c0 + 3) * 132 + kl] = v.w;
    }
    __syncthreads();

    // np-pairwise ||e||^2 (threads 0..127) and ||z||^2 (threads 128..191).
    // zsq from (2z): every intermediate is exactly 4x the z version -> x0.25.
    if (tid < 128) {
        float r[8];
#pragma unroll
        for (int j = 0; j < 8; ++j) {
            float v = s_b[j * 132 + tid];
            r[j] = __fmul_rn(v, v);
        }
#pragma unroll
        for (int i = 8; i < 64; i += 8)
#pragma unroll
            for (int j = 0; j < 8; ++j) {
                float v = s_b[(i + j) * 132 + tid];
                r[j] = __fadd_rn(r[j], __fmul_rn(v, v));
            }
        s_esq[tid] = __fadd_rn(
            __fadd_rn(__fadd_rn(r[0], r[1]), __fadd_rn(r[2], r[3])),
            __fadd_rn(__fadd_rn(r[4], r[5]), __fadd_rn(r[6], r[7])));
    } else if (tid < 192) {
        int m = tid - 128;
        float r[8];
#pragma unroll
        for (int j = 0; j < 8; ++j) {
            float v = s_a[j * 64 + m];
            r[j] = __fmul_rn(v, v);
        }
#pragma unroll
        for (int i = 8; i < 64; i += 8)
#pragma unroll
            for (int j = 0; j < 8; ++j) {
                float v = s_a[(i + j) * 64 + m];
                r[j] = __fadd_rn(r[j], __fmul_rn(v, v));
            }
        s_zsq[m] = __fmul_rn(0.25f, __fadd_rn(
            __fadd_rn(__fadd_rn(r[0], r[1]), __fadd_rn(r[2], r[3])),
            __fadd_rn(__fadd_rn(r[4], r[5]), __fadd_rn(r[6], r[7]))));
    }
    __syncthreads();

    int mi = tid & 15, ki = tid >> 4;
    int mbase = mi * 4, kbase = ki * 8;

    float acc[4][8];
#pragma unroll
    for (int mu = 0; mu < 4; ++mu)
#pragma unroll
        for (int ku = 0; ku < 8; ++ku) acc[mu][ku] = 0.f;

#pragma unroll 4
    for (int c = 0; c < 64; ++c) {
        float4 av = *(const float4*)(s_a + c * 64 + mbase);
        float4 b0 = *(const float4*)(s_b + c * 132 + kbase);
        float4 b1 = *(const float4*)(s_b + c * 132 + kbase + 4);
        const float* bv = &b0.x;  // b0,b1 contiguous? use explicit pairs instead
#pragma unroll
        for (int mu = 0; mu < 4; ++mu) {
            float a = (&av.x)[mu];
            acc[mu][0] = __fmaf_rn(a, b0.x, acc[mu][0]);
            acc[mu][1] = __fmaf_rn(a, b0.y, acc[mu][1]);
            acc[mu][2] = __fmaf_rn(a, b0.z, acc[mu][2]);
            acc[mu][3] = __fmaf_rn(a, b0.w, acc[mu][3]);
            acc[mu][4] = __fmaf_rn(a, b1.x, acc[mu][4]);
            acc[mu][5] = __fmaf_rn(a, b1.y, acc[mu][5]);
            acc[mu][6] = __fmaf_rn(a, b1.z, acc[mu][6]);
            acc[mu][7] = __fmaf_rn(a, b1.w, acc[mu][7]);
        }
        (void)bv;
    }

    // d = fl(fl(zsq+esq) - dot2); per-m argmin over this thread's 8 k (ascending)
    float zs[4], es[8];
#pragma unroll
    for (int mu = 0; mu < 4; ++mu) zs[mu] = s_zsq[mbase + mu];
#pragma unroll
    for (int ku = 0; ku < 8; ++ku) es[ku] = s_esq[kbase + ku];

    float bd[4];
    int bix[4];
#pragma unroll
    for (int mu = 0; mu < 4; ++mu) {
        float best = 3.4e38f;
        int bi = k0 + kbase;
#pragma unroll
        for (int ku = 0; ku < 8; ++ku) {
            float d = __fsub_rn(__fadd_rn(zs[mu], es[ku]), acc[mu][ku]);
            if (d < best) { best = d; bi = k0 + kbase + ku; }  // strict <
        }
        bd[mu] = best;
        bix[mu] = bi;
    }

    __syncthreads();  // done reading s_a; reuse it for the ki-merge
    float* red_d = s_a;                 // [16][64]
    int* red_i = (int*)(s_a + 1024);    // [16][64]
#pragma unroll
    for (int mu = 0; mu < 4; ++mu) {
        red_d[ki * 64 + mbase + mu] = bd[mu];
        red_i[ki * 64 + mbase + mu] = bix[mu];
    }
    __syncthreads();
    if (tid < MT) {
        float best = red_d[tid];
        int bi = red_i[tid];
#pragma unroll
        for (int q = 1; q < 16; ++q) {  // ascending ki -> first-index ties
            float d = red_d[q * 64 + tid];
            int i = red_i[q * 64 + tid];
            if (d < best) { best = d; bi = i; }
        }
        pdist[blockIdx.y * NVEC + n0 + tid] = best;
        pidx[blockIdx.y * NVEC + n0 + tid] = bi;
    }
}

// Merge 8 chunks (ascending -> first-index ties); write idx; write FULL one-hot
// rows (replaces memset). 512 blocks x 64 rows (2 blocks/CU).
__global__ void __launch_bounds__(256) k_combine(const float* __restrict__ pdist,
                                                 int* __restrict__ pidx,
                                                 float* __restrict__ out) {
    __shared__ int sbi[64];
    int n0 = blockIdx.x * 64;
    if (threadIdx.x < 64) {
        int n = n0 + threadIdx.x;
        float best = pdist[n];
        int bi = pidx[n];
#pragma unroll
        for (int q = 1; q < NCHUNK; ++q) {
            float d = pdist[q * NVEC + n];
            int i = pidx[q * NVEC + n];
            if (d < best) { best = d; bi = i; }
        }
        pidx[n] = bi;  // final idx (own slot only)
        out[O_IDX + n] = (float)bi;
        sbi[threadIdx.x] = bi;
    }
    __syncthreads();
    int wave = threadIdx.x >> 6, lane = threadIdx.x & 63;
    size_t base = (size_t)O_MINENC + (size_t)n0 * NE;
    for (int r = wave; r < 64; r += 4) {
        int rbi = sbi[r];
        float* rp = out + base + (size_t)r * NE;
#pragma unroll
        for (int s = 0; s < 8; ++s) {
            int col = s * 128 + lane * 2;
            float2 v;
            v.x = (col == rbi) ? 1.0f : 0.0f;
            v.y = (col + 1 == rbi) ? 1.0f : 0.0f;
            *(float2*)(rp + col) = v;
        }
    }
}

// Gather-based segment sum: one block per code k, 4 waves. Ballot-scan idx;
// members accumulated lane=element; popcount -> cs. Deterministic. No atomics.
__global__ void __launch_bounds__(256) k_sumenc(const int* __restrict__ idx,
                                                const float* __restrict__ z,
                                                float* __restrict__ cs,
                                                float* __restrict__ sumenc) {
    int k = blockIdx.x;
    int wave = threadIdx.x >> 6, lane = threadIdx.x & 63;
    float acc = 0.f;
    int cnt = 0;
    int base = wave * 8192;
    for (int it = 0; it < 128; ++it) {
        int n0 = base + it * 64;
        int idv = idx[n0 + lane];
        unsigned long long m = __ballot(idv == k);
        cnt += __popcll(m);
        while (m) {
            int bit = __ffsll((unsigned long long)m) - 1;  // ascending n
            m &= m - 1;
            int n = n0 + bit;
            int b = n >> 10, hw = n & 1023;
            acc = __fadd_rn(acc, z[b * 65536 + lane * 1024 + hw]);  // element c = lane
        }
    }
    __shared__ float sacc[4][64];
    __shared__ int scnt[4];
    sacc[wave][lane] = acc;
    if (lane == 0) scnt[wave] = cnt;
    __syncthreads();
    if (wave == 0) {
        float t = __fadd_rn(__fadd_rn(sacc[0][lane], sacc[1][lane]),
                            __fadd_rn(sacc[2][lane], sacc[3][lane]));
        sumenc[k * ED + lane] = t;
        if (lane == 0) cs[k] = (float)(scnt[0] + scnt[1] + scnt[2] + scnt[3]);
    }
}

// Single block, 1024 threads: EMA cluster-size + ntot/entropy reductions +
// perplexity + codebook update. Fused.
__global__ void __launch_bounds__(1024) k_ema(const float* __restrict__ ema_cs,
                                              const float* __restrict__ ema_w,
                                              const float* __restrict__ cs,
                                              const float* __restrict__ sumenc,
                                              float* __restrict__ newemb,
                                              float* __restrict__ out) {
    int k = threadIdx.x;  // 0..1023 == NE
    float c = cs[k];
    float ncs = 0.99f * ema_cs[k] + (1.0f - 0.99f) * c;
    float p = c * (1.0f / (float)NVEC);
    float e = p * logf(p + 1e-10f);
    float rn_ = ncs, re_ = e;
#pragma unroll
    for (int o = 32; o > 0; o >>= 1) {
        rn_ += __shfl_down(rn_, o, 64);
        re_ += __shfl_down(re_, o, 64);
    }
    __shared__ float sn[16], se_[16];
    __shared__ float s_n;
    int wave = k >> 6, lane = k & 63;
    if (lane == 0) { sn[wave] = rn_; se_[wave] = re_; }
    __syncthreads();
    if (k == 0) {
        float tn = 0.f, te = 0.f;
#pragma unroll
        for (int w = 0; w < 16; ++w) { tn += sn[w]; te += se_[w]; }
        s_n = tn;
        out[O_PERP] = expf(-te);
    }
    __syncthreads();
    float nt = s_n;
    float csn = (ncs + 1e-5f) / (nt + 1024.0f * 1e-5f) * nt;
    __shared__ float s_csn[NE];
    s_csn[k] = csn;
    __syncthreads();
    for (int t = k; t < NE * ED; t += 1024) {  // coalesced
        float nw = 0.99f * ema_w[t] + (1.0f - 0.99f) * sumenc[t];
        newemb[t] = nw / s_csn[t >> 6];
    }
}

// 2048 blocks x 256 threads x 4 elems. Per-block partial loss, one plain store.
__global__ void __launch_bounds__(256) k_zq(const float* __restrict__ z,
                                            const int* __restrict__ idx,
                                            const float* __restrict__ newemb,
                                            float* __restrict__ out,
                                            float* __restrict__ lossp) {
    float local = 0.f;
#pragma unroll
    for (int i = 0; i < 4; ++i) {
        int t = blockIdx.x * 256 + threadIdx.x + i * 524288;
        int b = t >> 16, c = (t >> 10) & 63, hw = t & 1023;
        int n = (b << 10) | hw;
        float e = newemb[idx[n] * ED + c];
        float zv = z[t];
        float diff = e - zv;             // z_q - z
        out[O_ZQ + t] = zv + diff;       // straight-through: z + (z_q - z)
        local = fmaf(diff, diff, local);
    }
#pragma unroll
    for (int o = 32; o > 0; o >>= 1) local += __shfl_down(local, o, 64);
    __shared__ float sp[4];
    int wave = threadIdx.x >> 6;
    if ((threadIdx.x & 63) == 0) sp[wave] = local;
    __syncthreads();
    if (threadIdx.x == 0)
        lossp[blockIdx.x] = (sp[0] + sp[1]) + (sp[2] + sp[3]);
}

// One block, 256 threads: reduce 2048 partials -> loss.
__global__ void __launch_bounds__(256) k_fin(const float* __restrict__ lossp,
                                             float* __restrict__ out) {
    float v = 0.f;
#pragma unroll
    for (int i = 0; i < 8; ++i) v += lossp[i * 256 + threadIdx.x];
#pragma unroll
    for (int o = 32; o > 0; o >>= 1) v += __shfl_down(v, o, 64);
    __shared__ float sp[4];
    int wave = threadIdx.x >> 6;
    if ((threadIdx.x & 63) == 0) sp[wave] = v;
    __syncthreads();
    if (threadIdx.x == 0)
        out[O_LOSS] = 0.25f * (((sp[0] + sp[1]) + (sp[2] + sp[3])) * (1.0f / (float)TOT));
}

extern "C" void kernel_launch(void* const* d_in, const int* in_sizes, int n_in,
                              void* d_out, int out_size, void* d_ws, size_t ws_size,
                              hipStream_t stream) {
    const float* z      = (const float*)d_in[0];
    const float* emb    = (const float*)d_in[1];
    const float* ema_cs = (const float*)d_in[2];
    const float* ema_w  = (const float*)d_in[3];
    float* out = (float*)d_out;
    float* ws  = (float*)d_ws;

    k_dist<<<dim3(512, NCHUNK), 256, 0, stream>>>(z, emb, ws + W_PDIST,
                                                  (int*)(ws + W_PIDX));
    k_combine<<<512, 256, 0, stream>>>(ws + W_PDIST, (int*)(ws + W_PIDX), out);
    k_sumenc<<<NE, 256, 0, stream>>>((const int*)(ws + W_PIDX), z, ws + W_CS,
                                     ws + W_SUMENC);
    k_ema<<<1, 1024, 0, stream>>>(ema_cs, ema_w, ws + W_CS, ws + W_SUMENC,
                                  ws + W_NEWEMB, out);
    k_zq<<<2048, 256, 0, stream>>>(z, (const int*)(ws + W_PIDX), ws + W_NEWEMB, out,
                                   ws + W_LOSSP);
    k_fin<<<1, 256, 0, stream>>>(ws + W_LOSSP, out);
}